// Round 16
// baseline (199.826 us; speedup 1.0000x reference)
//
#include <hip/hip_runtime.h>
#include <cstdint>
#include <cstddef>

typedef float f32x4 __attribute__((ext_vector_type(4)));
typedef float f32x16 __attribute__((ext_vector_type(16)));
typedef __bf16 bf16x8 __attribute__((ext_vector_type(8)));

#define BB 16
#define SEQ 1024
#define DMODEL 768
#define NHEAD 12
#define HDIM 64
#define MTOT (BB * SEQ)
#define NQKV (3 * DMODEL)
#define NQK (2 * DMODEL)   // natural-layout Q|K row length
// 0.125 (hd^-0.5) * log2(e): QK^T then exp2 == exp(0.125 * qk)
#define QSCALE 0.18033688011112042f

static __device__ __forceinline__ unsigned short f2bf(float f) {
  unsigned int u = __builtin_bit_cast(unsigned int, f);
  u += 0x7fffu + ((u >> 16) & 1u);
  return (unsigned short)(u >> 16);
}

static __device__ __forceinline__ unsigned cvt_pk_bf16(float lo, float hi) {
  unsigned r;
  asm("v_cvt_pk_bf16_f32 %0, %1, %2" : "=v"(r) : "v"(lo), "v"(hi));
  return r;
}

static __device__ __forceinline__ float max3f(float a, float b, float c) {
  return fmaxf(fmaxf(a, b), c);   // clang fuses to v_max3_f32 (T17)
}

static __device__ __forceinline__ void gload_lds16(const void* g, void* l) {
  __builtin_amdgcn_global_load_lds((__attribute__((address_space(1))) void*)g,
                                   (__attribute__((address_space(3))) void*)l,
                                   16, 0, 0);
}

// ---- fused prep: x->bf16 cvt (blocks 0..1023) + both weight transposes ----
__global__ __launch_bounds__(256) void k_prep(
    const float4* __restrict__ x4, ushort4* __restrict__ xb4,
    const float* __restrict__ qkv_w, unsigned short* __restrict__ WqT,
    const float* __restrict__ proj_w, unsigned short* __restrict__ WpT) {
  const int blk = blockIdx.x;
  if (blk < 1024) {
    const int n4 = MTOT * DMODEL / 4;
    const int stride = 1024 * 256;
    for (int i = blk * 256 + threadIdx.x; i < n4; i += stride) {
      float4 v = x4[i];
      ushort4 o;
      o.x = f2bf(v.x); o.y = f2bf(v.y); o.z = f2bf(v.z); o.w = f2bf(v.w);
      xb4[i] = o;
    }
    return;
  }
  __shared__ float tile[32][33];
  const float* in; unsigned short* out; int C, scaleN, bx, by;
  if (blk < 1024 + 1728) {
    const int l = blk - 1024; bx = l % 72; by = l / 72;
    in = qkv_w; out = WqT; C = NQKV; scaleN = DMODEL;
  } else {
    const int l = blk - 2752; bx = l % 24; by = l / 24;
    in = proj_w; out = WpT; C = DMODEL; scaleN = 0;
  }
  const int R = DMODEL;
  const int tx = threadIdx.x & 31, ty = threadIdx.x >> 5;
  const int c0 = bx * 32, r0 = by * 32;
#pragma unroll
  for (int i = 0; i < 4; ++i)
    tile[ty + i * 8][tx] = in[(size_t)(r0 + ty + i * 8) * C + c0 + tx];
  __syncthreads();
#pragma unroll
  for (int i = 0; i < 4; ++i) {
    const int n = c0 + ty + i * 8;  // original column = output row
    float v = tile[tx][ty + i * 8];
    if (n < scaleN) v *= QSCALE;
    out[(size_t)n * R + r0 + tx] = f2bf(v);
  }
}

// ---- GEMM C[M,N] = A[M,K] * Bt[N,K]^T, bf16 in, f32 accum (R12/R14 exact) ----
template <int MODE>
__global__ __launch_bounds__(256, 4) void k_gemm_bt(
    const unsigned short* __restrict__ A, const unsigned short* __restrict__ Bt,
    int M, int N, int K,
    float* __restrict__ outF, const float* __restrict__ bias,
    unsigned short* __restrict__ QK, unsigned short* __restrict__ Vt) {
  __shared__ __align__(16) unsigned short As[128 * 64];  // 16 KB
  __shared__ __align__(16) unsigned short Bs[128 * 64];  // 16 KB
  const int tid = threadIdx.x;
  const int lane = tid & 63, wid = tid >> 6;
  const int ln15 = lane & 15, lh = lane >> 4;
  const int wr = wid >> 1, wc = wid & 1;
  const int m0 = blockIdx.x * 128, n0 = blockIdx.y * 128;
  f32x4 acc[4][4] = {};
  const int srow = lane >> 3;
  const int sblk = ((lane & 7) ^ srow) * 8;
  const int swz = (ln15 & 7) << 3;
  const int nk = K >> 6;

  for (int kt = 0; kt < nk; ++kt) {
    const int k0 = kt * 64;
#pragma unroll
    for (int c = 0; c < 4; ++c) {
      const int ch = wid * 4 + c;
      const int row = ch * 8 + srow;
      gload_lds16(A + (size_t)(m0 + row) * K + k0 + sblk, &As[ch * 512]);
      gload_lds16(Bt + (size_t)(n0 + row) * K + k0 + sblk, &Bs[ch * 512]);
    }
    __syncthreads();
#pragma unroll
    for (int kk = 0; kk < 2; ++kk) {
      const int kc = kk * 32 + lh * 8;
      bf16x8 af[4], bfv[4];
#pragma unroll
      for (int mt = 0; mt < 4; ++mt)
        af[mt] = *reinterpret_cast<const bf16x8*>(
            &As[(wr * 64 + mt * 16 + ln15) * 64 + (kc ^ swz)]);
#pragma unroll
      for (int nn = 0; nn < 4; ++nn)
        bfv[nn] = *reinterpret_cast<const bf16x8*>(
            &Bs[(wc * 64 + nn * 16 + ln15) * 64 + (kc ^ swz)]);
#pragma unroll
      for (int mt = 0; mt < 4; ++mt)
#pragma unroll
        for (int nn = 0; nn < 4; ++nn)
          acc[mt][nn] = __builtin_amdgcn_mfma_f32_16x16x32_bf16(af[mt], bfv[nn], acc[mt][nn], 0, 0, 0);
    }
    __syncthreads();
  }

#pragma unroll
  for (int mt = 0; mt < 4; ++mt) {
#pragma unroll
    for (int nn = 0; nn < 4; ++nn) {
      const int nb = n0 + wc * 64 + nn * 16;
      const int mb = m0 + wr * 64 + mt * 16 + lh * 4;
      if (MODE == 0) {
#pragma unroll
        for (int r = 0; r < 4; ++r)
          outF[(size_t)(mb + r) * N + nb + ln15] = acc[mt][nn][r] + bias[nb + ln15];
      } else if (nb < NQK) {
#pragma unroll
        for (int r = 0; r < 4; ++r)
          QK[(size_t)(mb + r) * NQK + nb + ln15] = f2bf(acc[mt][nn][r]);
      } else {
        const int rr = nb + ln15 - NQK;
        const int h = rr >> 6, d = rr & 63;
        const int b = mb >> 10, nr0 = mb & 1023;
        ushort4 u;
        u.x = f2bf(acc[mt][nn][0]); u.y = f2bf(acc[mt][nn][1]);
        u.z = f2bf(acc[mt][nn][2]); u.w = f2bf(acc[mt][nn][3]);
        *reinterpret_cast<ushort4*>(
            &Vt[(((size_t)b * NHEAD + h) * HDIM + d) * SEQ + nr0]) = u;
      }
    }
  }
}

// ---- fused flash attention on 32x32 MFMA fragments ----
// QBLK=128, 4 waves x 32 q-rows each (wave-tile doubled -> K/V LDS reads per q
// HALVE vs 16x16; attn was LDS-pipe-bound). Swapped QK^T: mfma(A=K, B=Q) ->
// col=lane&31=q (one q per lane), rows=kpos=(reg&3)+8*(reg>>2)+4*(lane>>5).
// C-fold (-mr), ones-MFMA row-sum (4x 32x32; output layout == PV output layout
// so 1/accl needs no shuffle), defer-max with xor32 lane-pair combine.
// K/V staged with the proven inverse-swizzled global_load_lds (rule 21).
__global__ __launch_bounds__(256, 4) void k_attn(
    const unsigned short* __restrict__ QKn, const unsigned short* __restrict__ Vt,
    unsigned short* __restrict__ O) {
  __shared__ __align__(16) unsigned short Ks[64 * 64];      // [kpos][d], swizzled
  __shared__ __align__(16) unsigned short Vs[64 * 64];      // [d][kpos], swizzled
  __shared__ __align__(16) unsigned short Ps[4][32 * 72];   // per-wave P [q][kpos]
  const int tid = threadIdx.x;
  const int lane = tid & 63, w = tid >> 6;
  const int ln31 = lane & 31, lh1 = lane >> 5;
  const int o = blockIdx.x;
  const int sid = (o & 7) * 192 + (o >> 3);
  const int qb = sid & 7;
  const int bhid = sid >> 3;
  const int h = bhid % NHEAD;
  const int b = bhid / NHEAD;
  const size_t bh = (size_t)(b * NHEAD + h);
  const unsigned short* Qrow = QKn + (size_t)(b * SEQ + qb * 128 + w * 32 + ln31) * NQK + h * HDIM;
  const unsigned short* Kbase = QKn + (size_t)(b * SEQ) * NQK + DMODEL + h * HDIM;
  const unsigned short* Vbase = Vt + bh * HDIM * SEQ;

  const int srow = lane >> 3;
  const int sblk = ((lane & 7) ^ srow) * 8;
  const int rsw = ln31 & 7;   // read-side row-XOR

  // Q fragment (B-operand): col=q=ln31, k(d) = ks*16 + lh1*8 + j
  bf16x8 aq[4];
#pragma unroll
  for (int ks = 0; ks < 4; ++ks)
    aq[ks] = *reinterpret_cast<const bf16x8*>(Qrow + ks * 16 + lh1 * 8);

  bf16x8 onesb;
#pragma unroll
  for (int i = 0; i < 8; ++i) onesb[i] = (__bf16)1.0f;

  f32x16 acc0 = {}, acc1 = {};   // O tiles d 0-31 / 32-63
  f32x16 accl = {};              // row-sums; reg i <-> q=(i&3)+8*(i>>2)+4*lh1
  float mr = 0.f;                // running max (log2 domain)

  for (int kb = 0; kb < SEQ / 64; ++kb) {
#pragma unroll
    for (int c = 0; c < 2; ++c) {  // 8 chunks each; 4 waves take 2+2
      const int ch = w * 2 + c;
      const int row = ch * 8 + srow;
      gload_lds16(Kbase + (size_t)(kb * 64 + row) * NQK + sblk, &Ks[ch * 512]);
      gload_lds16(Vbase + (size_t)row * SEQ + kb * 64 + sblk, &Vs[ch * 512]);
    }
    __syncthreads();

    // S^T = K Q^T with C = -mr; sv0: kpos 0-31, sv1: kpos 32-63
    const float nmr = -mr;
    f32x16 sv0, sv1;
#pragma unroll
    for (int i = 0; i < 16; ++i) { sv0[i] = nmr; sv1[i] = nmr; }
    __builtin_amdgcn_s_setprio(1);
#pragma unroll
    for (int ks = 0; ks < 4; ++ks) {
      const int bo = (((ks * 2 + lh1) ^ rsw) << 3);
      bf16x8 bk0 = *reinterpret_cast<const bf16x8*>(&Ks[ln31 * 64 + bo]);
      sv0 = __builtin_amdgcn_mfma_f32_32x32x16_bf16(bk0, aq[ks], sv0, 0, 0, 0);
      bf16x8 bk1 = *reinterpret_cast<const bf16x8*>(&Ks[(32 + ln31) * 64 + bo]);
      sv1 = __builtin_amdgcn_mfma_f32_32x32x16_bf16(bk1, aq[ks], sv1, 0, 0, 0);
    }
    __builtin_amdgcn_s_setprio(0);

    // in-lane partial max over 32 vals (balanced max3 tree, depth 3)
    float pm;
    {
      const float a0 = max3f(sv0[0], sv0[1], sv0[2]);
      const float a1 = max3f(sv0[3], sv0[4], sv0[5]);
      const float a2 = max3f(sv0[6], sv0[7], sv0[8]);
      const float a3 = max3f(sv0[9], sv0[10], sv0[11]);
      const float a4 = max3f(sv0[12], sv0[13], sv0[14]);
      const float b0 = max3f(sv0[15], sv1[0], sv1[1]);
      const float b1 = max3f(sv1[2], sv1[3], sv1[4]);
      const float b2 = max3f(sv1[5], sv1[6], sv1[7]);
      const float b3 = max3f(sv1[8], sv1[9], sv1[10]);
      const float b4 = max3f(sv1[11], sv1[12], sv1[13]);
      const float c0 = max3f(a0, a1, a2);
      const float c1 = max3f(a3, a4, b0);
      const float c2 = max3f(b1, b2, b3);
      const float c3 = max3f(b4, sv1[14], sv1[15]);
      pm = fmaxf(fmaxf(c0, c1), fmaxf(c2, c3));
    }
    // defer-max: rescale only when some row grew past +8 (P bounded by 2^8)
    if (__any(pm > 8.f)) {
      const float bmf = fmaxf(pm, __shfl_xor(pm, 32));  // full-row max (lane pair)
      const float delta = fmaxf(bmf, 0.f);
      const float al = __builtin_amdgcn_exp2f(-delta);
#pragma unroll
      for (int i = 0; i < 16; ++i) { sv0[i] -= delta; sv1[i] -= delta; }
      mr += delta;
      float alq[16];
#pragma unroll
      for (int i = 0; i < 16; ++i)
        alq[i] = __shfl(al, (i & 3) + 8 * (i >> 2) + 4 * lh1);
#pragma unroll
      for (int i = 0; i < 16; ++i) {
        acc0[i] *= alq[i]; acc1[i] *= alq[i]; accl[i] *= alq[i];
      }
    }

#pragma unroll
    for (int i = 0; i < 16; ++i) {
      sv0[i] = __builtin_amdgcn_exp2f(sv0[i]);
      sv1[i] = __builtin_amdgcn_exp2f(sv1[i]);
    }

    // pack P -> LDS: Ps[q=ln31][kpos]; reg 4g+r of tile tk is kpos tk*32+8g+4*lh1+r
#pragma unroll
    for (int g = 0; g < 4; ++g) {
      uint2 u;
      u.x = cvt_pk_bf16(sv0[g * 4 + 0], sv0[g * 4 + 1]);
      u.y = cvt_pk_bf16(sv0[g * 4 + 2], sv0[g * 4 + 3]);
      *reinterpret_cast<uint2*>(&Ps[w][ln31 * 72 + g * 8 + lh1 * 4]) = u;
      uint2 v;
      v.x = cvt_pk_bf16(sv1[g * 4 + 0], sv1[g * 4 + 1]);
      v.y = cvt_pk_bf16(sv1[g * 4 + 2], sv1[g * 4 + 3]);
      *reinterpret_cast<uint2*>(&Ps[w][ln31 * 72 + 32 + g * 8 + lh1 * 4]) = v;
    }

    // P A-fragments: row=q=ln31, k(kpos) = ks*16 + lh1*8 + j
    bf16x8 ap[4];
#pragma unroll
    for (int ks = 0; ks < 4; ++ks)
      ap[ks] = *reinterpret_cast<const bf16x8*>(&Ps[w][ln31 * 72 + ks * 16 + lh1 * 8]);

    __builtin_amdgcn_s_setprio(1);
#pragma unroll
    for (int ks = 0; ks < 4; ++ks)   // row-sum MFMA
      accl = __builtin_amdgcn_mfma_f32_32x32x16_bf16(ap[ks], onesb, accl, 0, 0, 0);
#pragma unroll
    for (int ks = 0; ks < 4; ++ks) { // O += P V
      const int bo = (((ks * 2 + lh1) ^ rsw) << 3);
      bf16x8 bv0 = *reinterpret_cast<const bf16x8*>(&Vs[ln31 * 64 + bo]);
      acc0 = __builtin_amdgcn_mfma_f32_32x32x16_bf16(ap[ks], bv0, acc0, 0, 0, 0);
      bf16x8 bv1 = *reinterpret_cast<const bf16x8*>(&Vs[(32 + ln31) * 64 + bo]);
      acc1 = __builtin_amdgcn_mfma_f32_32x32x16_bf16(ap[ks], bv1, acc1, 0, 0, 0);
    }
    __builtin_amdgcn_s_setprio(0);
    __syncthreads();
  }

  const int qg = b * SEQ + qb * 128 + w * 32;
#pragma unroll
  for (int i = 0; i < 16; ++i) {
    const int qrow = (i & 3) + 8 * (i >> 2) + 4 * lh1;
    const float rl = 1.0f / accl[i];
    O[(size_t)(qg + qrow) * DMODEL + h * 64 + ln31]      = f2bf(acc0[i] * rl);
    O[(size_t)(qg + qrow) * DMODEL + h * 64 + 32 + ln31] = f2bf(acc1[i] * rl);
  }
}

extern "C" void kernel_launch(void* const* d_in, const int* in_sizes, int n_in,
                              void* d_out, int out_size, void* d_ws, size_t ws_size,
                              hipStream_t stream) {
  const float* x      = (const float*)d_in[0];
  const float* qkv_w  = (const float*)d_in[1];
  const float* proj_w = (const float*)d_in[2];
  const float* proj_b = (const float*)d_in[3];
  float* out = (float*)d_out;

  char* ws = (char*)d_ws;
  const size_t SZ_XB   = (size_t)MTOT * DMODEL * 2;   // x bf16; reused as attn-out bf16
  const size_t SZ_WQT  = (size_t)NQKV * DMODEL * 2;
  const size_t SZ_WPT  = (size_t)DMODEL * DMODEL * 2;
  const size_t SZ_QK   = (size_t)MTOT * NQK * 2;      // natural Q|K [m][1536]
  const size_t SZ_VT   = (size_t)BB * NHEAD * HDIM * SEQ * 2;
  unsigned short* Xb   = (unsigned short*)ws;
  unsigned short* WqT  = (unsigned short*)(ws + SZ_XB);
  unsigned short* WpT  = (unsigned short*)(ws + SZ_XB + SZ_WQT);
  unsigned short* QKn  = (unsigned short*)(ws + SZ_XB + SZ_WQT + SZ_WPT);
  unsigned short* Vt   = (unsigned short*)(ws + SZ_XB + SZ_WQT + SZ_WPT + SZ_QK);
  if (ws_size < SZ_XB + SZ_WQT + SZ_WPT + SZ_QK + SZ_VT) return;

  // 1) fused prep: x->bf16 + both weight transposes (Q-cols pre-scaled by QSCALE)
  k_prep<<<3328, 256, 0, stream>>>((const float4*)x, (ushort4*)Xb,
                                   qkv_w, WqT, proj_w, WpT);
  // 2) QKV projection -> natural Q|K [m][1536] + packed V^T. 128^2 tiles, m-fastest.
  k_gemm_bt<1><<<dim3(MTOT / 128, NQKV / 128), 256, 0, stream>>>(
      Xb, WqT, MTOT, NQKV, DMODEL, nullptr, nullptr, QKn, Vt);
  // 3) fused attention -> Oattn (reuses Xb region; Xb is dead after step 2)
  k_attn<<<BB * NHEAD * 8, 256, 0, stream>>>(QKn, Vt, Xb);
  // 4) output projection + bias -> f32 out
  k_gemm_bt<0><<<dim3(MTOT / 128, DMODEL / 128), 256, 0, stream>>>(
      Xb, WpT, MTOT, DMODEL, DMODEL, out, proj_b, nullptr, nullptr);
}

// Round 17
// 167.803 us; speedup vs baseline: 1.1908x; 1.1908x over previous
//
#include <hip/hip_runtime.h>
#include <cstdint>
#include <cstddef>

typedef float f32x4 __attribute__((ext_vector_type(4)));
typedef __bf16 bf16x8 __attribute__((ext_vector_type(8)));

#define BB 16
#define SEQ 1024
#define DMODEL 768
#define NHEAD 12
#define HDIM 64
#define MTOT (BB * SEQ)
#define NQKV (3 * DMODEL)
#define NQK (2 * DMODEL)   // natural-layout Q|K row length
// 0.125 (hd^-0.5) * log2(e): QK^T then exp2 == exp(0.125 * qk)
#define QSCALE 0.18033688011112042f

static __device__ __forceinline__ unsigned short f2bf(float f) {
  unsigned int u = __builtin_bit_cast(unsigned int, f);
  u += 0x7fffu + ((u >> 16) & 1u);
  return (unsigned short)(u >> 16);
}

static __device__ __forceinline__ unsigned cvt_pk_bf16(float lo, float hi) {
  unsigned r;
  asm("v_cvt_pk_bf16_f32 %0, %1, %2" : "=v"(r) : "v"(lo), "v"(hi));
  return r;
}

static __device__ __forceinline__ float max3f(float a, float b, float c) {
  return fmaxf(fmaxf(a, b), c);   // clang fuses to v_max3_f32 (T17)
}

static __device__ __forceinline__ void gload_lds16(const void* g, void* l) {
  __builtin_amdgcn_global_load_lds((__attribute__((address_space(1))) void*)g,
                                   (__attribute__((address_space(3))) void*)l,
                                   16, 0, 0);
}

// ---- fused prep: x->bf16 cvt (blocks 0..1023) + both weight transposes ----
__global__ __launch_bounds__(256) void k_prep(
    const float4* __restrict__ x4, ushort4* __restrict__ xb4,
    const float* __restrict__ qkv_w, unsigned short* __restrict__ WqT,
    const float* __restrict__ proj_w, unsigned short* __restrict__ WpT) {
  const int blk = blockIdx.x;
  if (blk < 1024) {
    const int n4 = MTOT * DMODEL / 4;
    const int stride = 1024 * 256;
    for (int i = blk * 256 + threadIdx.x; i < n4; i += stride) {
      float4 v = x4[i];
      ushort4 o;
      o.x = f2bf(v.x); o.y = f2bf(v.y); o.z = f2bf(v.z); o.w = f2bf(v.w);
      xb4[i] = o;
    }
    return;
  }
  __shared__ float tile[32][33];
  const float* in; unsigned short* out; int C, scaleN, bx, by;
  if (blk < 1024 + 1728) {
    const int l = blk - 1024; bx = l % 72; by = l / 72;
    in = qkv_w; out = WqT; C = NQKV; scaleN = DMODEL;
  } else {
    const int l = blk - 2752; bx = l % 24; by = l / 24;
    in = proj_w; out = WpT; C = DMODEL; scaleN = 0;
  }
  const int R = DMODEL;
  const int tx = threadIdx.x & 31, ty = threadIdx.x >> 5;
  const int c0 = bx * 32, r0 = by * 32;
#pragma unroll
  for (int i = 0; i < 4; ++i)
    tile[ty + i * 8][tx] = in[(size_t)(r0 + ty + i * 8) * C + c0 + tx];
  __syncthreads();
#pragma unroll
  for (int i = 0; i < 4; ++i) {
    const int n = c0 + ty + i * 8;  // original column = output row
    float v = tile[tx][ty + i * 8];
    if (n < scaleN) v *= QSCALE;
    out[(size_t)n * R + r0 + tx] = f2bf(v);
  }
}

// ---- GEMM C[M,N] = A[M,K] * Bt[N,K]^T, bf16 in, f32 accum (R12 exact) ----
// 128x128 tile, BK=64 single-buffered (32 KB LDS), 2 barriers/K-step, 4 waves
// at 64x64 (acc 4x4 = 64 AGPR), 4 blocks/CU. T2 swizzle both-sides (rule 21).
// Proven negatives at this shape: issue-early dbuf (R13), 8-phase (R6),
// counted-vmcnt (R5), 256-wide tiles (R9), XCD supertiling (R15, null).
// MODE 0: outF = C + bias. MODE 1: natural Q|K [m][1536] + packed V^T.
template <int MODE>
__global__ __launch_bounds__(256, 4) void k_gemm_bt(
    const unsigned short* __restrict__ A, const unsigned short* __restrict__ Bt,
    int M, int N, int K,
    float* __restrict__ outF, const float* __restrict__ bias,
    unsigned short* __restrict__ QK, unsigned short* __restrict__ Vt) {
  __shared__ __align__(16) unsigned short As[128 * 64];  // 16 KB
  __shared__ __align__(16) unsigned short Bs[128 * 64];  // 16 KB
  const int tid = threadIdx.x;
  const int lane = tid & 63, wid = tid >> 6;
  const int ln15 = lane & 15, lh = lane >> 4;
  const int wr = wid >> 1, wc = wid & 1;
  const int m0 = blockIdx.x * 128, n0 = blockIdx.y * 128;
  f32x4 acc[4][4] = {};
  const int srow = lane >> 3;
  const int sblk = ((lane & 7) ^ srow) * 8;
  const int swz = (ln15 & 7) << 3;
  const int nk = K >> 6;

  for (int kt = 0; kt < nk; ++kt) {
    const int k0 = kt * 64;
#pragma unroll
    for (int c = 0; c < 4; ++c) {
      const int ch = wid * 4 + c;
      const int row = ch * 8 + srow;
      gload_lds16(A + (size_t)(m0 + row) * K + k0 + sblk, &As[ch * 512]);
      gload_lds16(Bt + (size_t)(n0 + row) * K + k0 + sblk, &Bs[ch * 512]);
    }
    __syncthreads();
#pragma unroll
    for (int kk = 0; kk < 2; ++kk) {
      const int kc = kk * 32 + lh * 8;
      bf16x8 af[4], bfv[4];
#pragma unroll
      for (int mt = 0; mt < 4; ++mt)
        af[mt] = *reinterpret_cast<const bf16x8*>(
            &As[(wr * 64 + mt * 16 + ln15) * 64 + (kc ^ swz)]);
#pragma unroll
      for (int nn = 0; nn < 4; ++nn)
        bfv[nn] = *reinterpret_cast<const bf16x8*>(
            &Bs[(wc * 64 + nn * 16 + ln15) * 64 + (kc ^ swz)]);
#pragma unroll
      for (int mt = 0; mt < 4; ++mt)
#pragma unroll
        for (int nn = 0; nn < 4; ++nn)
          acc[mt][nn] = __builtin_amdgcn_mfma_f32_16x16x32_bf16(af[mt], bfv[nn], acc[mt][nn], 0, 0, 0);
    }
    __syncthreads();
  }

#pragma unroll
  for (int mt = 0; mt < 4; ++mt) {
#pragma unroll
    for (int nn = 0; nn < 4; ++nn) {
      const int nb = n0 + wc * 64 + nn * 16;
      const int mb = m0 + wr * 64 + mt * 16 + lh * 4;
      if (MODE == 0) {
#pragma unroll
        for (int r = 0; r < 4; ++r)
          outF[(size_t)(mb + r) * N + nb + ln15] = acc[mt][nn][r] + bias[nb + ln15];
      } else if (nb < NQK) {
#pragma unroll
        for (int r = 0; r < 4; ++r)
          QK[(size_t)(mb + r) * NQK + nb + ln15] = f2bf(acc[mt][nn][r]);
      } else {
        const int rr = nb + ln15 - NQK;
        const int h = rr >> 6, d = rr & 63;
        const int b = mb >> 10, nr0 = mb & 1023;
        ushort4 u;
        u.x = f2bf(acc[mt][nn][0]); u.y = f2bf(acc[mt][nn][1]);
        u.z = f2bf(acc[mt][nn][2]); u.w = f2bf(acc[mt][nn][3]);
        *reinterpret_cast<ushort4*>(
            &Vt[(((size_t)b * NHEAD + h) * HDIM + d) * SEQ + nr0]) = u;
      }
    }
  }
}

// ---- fused flash attention, swapped-QK^T, low-VALU softmax (R14 exact) ----
// QBLK=128, 8 waves x 16 q. 16x16 fragments: the 128B K/V rows admit a full
// 8-way XOR swizzle over the 16-row read span -> 2-way (free); the 32x32
// variant (R16) cannot (8 blocks vs 32 rows -> 4-way conflict) and regressed.
__global__ __launch_bounds__(512) void k_attn(
    const unsigned short* __restrict__ QKn, const unsigned short* __restrict__ Vt,
    unsigned short* __restrict__ O) {
  __shared__ __align__(16) unsigned short Ks[64 * 64];      // [kpos][d], swizzled
  __shared__ __align__(16) unsigned short Vs[64 * 64];      // [d][kpos], swizzled
  __shared__ __align__(16) unsigned short Ps[8][16 * 72];   // per-wave P [q][kpos]
  const int tid = threadIdx.x;
  const int lane = tid & 63, w = tid >> 6;
  const int ln15 = lane & 15, lh = lane >> 4;
  const int o = blockIdx.x;
  const int sid = (o & 7) * 192 + (o >> 3);
  const int qb = sid & 7;
  const int bhid = sid >> 3;
  const int h = bhid % NHEAD;
  const int b = bhid / NHEAD;
  const size_t bh = (size_t)(b * NHEAD + h);
  const unsigned short* Qbase = QKn + (size_t)(b * SEQ + qb * 128 + w * 16) * NQK + h * HDIM;
  const unsigned short* Kbase = QKn + (size_t)(b * SEQ) * NQK + DMODEL + h * HDIM;
  const unsigned short* Vbase = Vt + bh * HDIM * SEQ;

  const int srow = lane >> 3;
  const int sblk = ((lane & 7) ^ srow) * 8;
  const int swz = (ln15 & 7) << 3;

  bf16x8 aq[2];
#pragma unroll
  for (int ch = 0; ch < 2; ++ch)
    aq[ch] = *reinterpret_cast<const bf16x8*>(Qbase + (size_t)ln15 * NQK + ch * 32 + lh * 8);

  bf16x8 onesb;
#pragma unroll
  for (int i = 0; i < 8; ++i) onesb[i] = (__bf16)1.0f;

  f32x4 acc[4] = {};
  f32x4 accl = {};          // row-sums via ones-MFMA; elem r <-> q-row lh*4+r
  float mr = 0.f;           // running max (log2 domain)
  f32x4 cinit = {};         // splat(-mr)

  for (int kb = 0; kb < SEQ / 64; ++kb) {
    {  // stage K/V tile kb (8 chunks each; wave w takes chunk w)
      const int row = w * 8 + srow;
      gload_lds16(Kbase + (size_t)(kb * 64 + row) * NQK + sblk, &Ks[w * 512]);
      gload_lds16(Vbase + (size_t)row * SEQ + kb * 64 + sblk, &Vs[w * 512]);
    }
    __syncthreads();

    // S^T = K Q^T with C = -mr  ->  sv holds (qk - mr)
    f32x4 sv[4];
#pragma unroll
    for (int t = 0; t < 4; ++t) sv[t] = cinit;
    __builtin_amdgcn_s_setprio(1);
#pragma unroll
    for (int t = 0; t < 4; ++t) {
#pragma unroll
      for (int ch = 0; ch < 2; ++ch) {
        bf16x8 bk = *reinterpret_cast<const bf16x8*>(
            &Ks[(t * 16 + ln15) * 64 + ((ch * 32 + lh * 8) ^ swz)]);
        sv[t] = __builtin_amdgcn_mfma_f32_16x16x32_bf16(bk, aq[ch], sv[t], 0, 0, 0);
      }
    }
    __builtin_amdgcn_s_setprio(0);

    // in-lane partial max: balanced max3 tree (7 ops, depth 3)
    float pm;
    {
      const float g0 = max3f(sv[0][0], sv[0][1], sv[0][2]);
      const float g1 = max3f(sv[0][3], sv[1][0], sv[1][1]);
      const float g2 = max3f(sv[1][2], sv[1][3], sv[2][0]);
      const float g3 = max3f(sv[2][1], sv[2][2], sv[2][3]);
      const float g4 = max3f(sv[3][0], sv[3][1], sv[3][2]);
      pm = fmaxf(max3f(g0, g1, g2), max3f(g3, g4, sv[3][3]));
    }
    // defer-max: rescale only when some row grew past +8 (P bounded by 2^8)
    if (__any(pm > 8.f)) {
      float bmf = pm;
      bmf = fmaxf(bmf, __shfl_xor(bmf, 16));
      bmf = fmaxf(bmf, __shfl_xor(bmf, 32));          // full-row (qk - mr) max
      const float delta = fmaxf(bmf, 0.f);
      const float al = __builtin_amdgcn_exp2f(-delta);
#pragma unroll
      for (int t = 0; t < 4; ++t)
#pragma unroll
        for (int r = 0; r < 4; ++r) sv[t][r] -= delta;
      mr += delta;
      cinit[0] = -mr; cinit[1] = -mr; cinit[2] = -mr; cinit[3] = -mr;
      float alq[4];
#pragma unroll
      for (int r = 0; r < 4; ++r) alq[r] = __shfl(al, lh * 4 + r);
#pragma unroll
      for (int dt = 0; dt < 4; ++dt)
#pragma unroll
        for (int r = 0; r < 4; ++r) acc[dt][r] *= alq[r];
#pragma unroll
      for (int r = 0; r < 4; ++r) accl[r] *= alq[r];
    }

#pragma unroll
    for (int t = 0; t < 4; ++t)
#pragma unroll
      for (int r = 0; r < 4; ++r) sv[t][r] = __builtin_amdgcn_exp2f(sv[t][r]);

    // pack P -> LDS (A-fragment redistribution)
#pragma unroll
    for (int t = 0; t < 4; ++t) {
      uint2 u;
      u.x = cvt_pk_bf16(sv[t][0], sv[t][1]);
      u.y = cvt_pk_bf16(sv[t][2], sv[t][3]);
      *reinterpret_cast<uint2*>(&Ps[w][ln15 * 72 + t * 16 + lh * 4]) = u;
    }

    bf16x8 ap[2];
#pragma unroll
    for (int ch = 0; ch < 2; ++ch)
      ap[ch] = *reinterpret_cast<const bf16x8*>(&Ps[w][ln15 * 72 + ch * 32 + lh * 8]);
    __builtin_amdgcn_s_setprio(1);
#pragma unroll
    for (int ch = 0; ch < 2; ++ch)   // row-sum MFMA
      accl = __builtin_amdgcn_mfma_f32_16x16x32_bf16(ap[ch], onesb, accl, 0, 0, 0);
#pragma unroll
    for (int dt = 0; dt < 4; ++dt) {
#pragma unroll
      for (int ch = 0; ch < 2; ++ch) {
        bf16x8 bv = *reinterpret_cast<const bf16x8*>(
            &Vs[(dt * 16 + ln15) * 64 + ((ch * 32 + lh * 8) ^ swz)]);
        acc[dt] = __builtin_amdgcn_mfma_f32_16x16x32_bf16(ap[ch], bv, acc[dt], 0, 0, 0);
      }
    }
    __builtin_amdgcn_s_setprio(0);
    __syncthreads();
  }

  const int qrow = qb * 128 + w * 16 + lh * 4;
#pragma unroll
  for (int dt = 0; dt < 4; ++dt)
#pragma unroll
    for (int r = 0; r < 4; ++r)
      O[((size_t)b * SEQ + qrow + r) * DMODEL + h * 64 + dt * 16 + ln15] =
          f2bf(acc[dt][r] / accl[r]);
}

extern "C" void kernel_launch(void* const* d_in, const int* in_sizes, int n_in,
                              void* d_out, int out_size, void* d_ws, size_t ws_size,
                              hipStream_t stream) {
  const float* x      = (const float*)d_in[0];
  const float* qkv_w  = (const float*)d_in[1];
  const float* proj_w = (const float*)d_in[2];
  const float* proj_b = (const float*)d_in[3];
  float* out = (float*)d_out;

  char* ws = (char*)d_ws;
  const size_t SZ_XB   = (size_t)MTOT * DMODEL * 2;   // x bf16; reused as attn-out bf16
  const size_t SZ_WQT  = (size_t)NQKV * DMODEL * 2;
  const size_t SZ_WPT  = (size_t)DMODEL * DMODEL * 2;
  const size_t SZ_QK   = (size_t)MTOT * NQK * 2;      // natural Q|K [m][1536]
  const size_t SZ_VT   = (size_t)BB * NHEAD * HDIM * SEQ * 2;
  unsigned short* Xb   = (unsigned short*)ws;
  unsigned short* WqT  = (unsigned short*)(ws + SZ_XB);
  unsigned short* WpT  = (unsigned short*)(ws + SZ_XB + SZ_WQT);
  unsigned short* QKn  = (unsigned short*)(ws + SZ_XB + SZ_WQT + SZ_WPT);
  unsigned short* Vt   = (unsigned short*)(ws + SZ_XB + SZ_WQT + SZ_WPT + SZ_QK);
  if (ws_size < SZ_XB + SZ_WQT + SZ_WPT + SZ_QK + SZ_VT) return;

  // 1) fused prep: x->bf16 + both weight transposes (Q-cols pre-scaled by QSCALE)
  k_prep<<<3328, 256, 0, stream>>>((const float4*)x, (ushort4*)Xb,
                                   qkv_w, WqT, proj_w, WpT);
  // 2) QKV projection -> natural Q|K [m][1536] + packed V^T. 128^2 tiles, m-fastest.
  k_gemm_bt<1><<<dim3(MTOT / 128, NQKV / 128), 256, 0, stream>>>(
      Xb, WqT, MTOT, NQKV, DMODEL, nullptr, nullptr, QKn, Vt);
  // 3) fused attention -> Oattn (reuses Xb region; Xb is dead after step 2)
  k_attn<<<BB * NHEAD * 8, 512, 0, stream>>>(QKn, Vt, Xb);
  // 4) output projection + bias -> f32 out
  k_gemm_bt<0><<<dim3(MTOT / 128, DMODEL / 128), 256, 0, stream>>>(
      Xb, WpT, MTOT, DMODEL, DMODEL, out, proj_b, nullptr, nullptr);
}

// Round 18
// 167.651 us; speedup vs baseline: 1.1919x; 1.0009x over previous
//
#include <hip/hip_runtime.h>
#include <cstdint>
#include <cstddef>

typedef float f32x4 __attribute__((ext_vector_type(4)));
typedef __bf16 bf16x8 __attribute__((ext_vector_type(8)));

#define BB 16
#define SEQ 1024
#define DMODEL 768
#define NHEAD 12
#define HDIM 64
#define MTOT (BB * SEQ)
#define NQKV (3 * DMODEL)
#define NQK (2 * DMODEL)   // natural-layout Q|K row length
// 0.125 (hd^-0.5) * log2(e): QK^T then exp2 == exp(0.125 * qk)
#define QSCALE 0.18033688011112042f

static __device__ __forceinline__ unsigned short f2bf(float f) {
  unsigned int u = __builtin_bit_cast(unsigned int, f);
  u += 0x7fffu + ((u >> 16) & 1u);
  return (unsigned short)(u >> 16);
}

static __device__ __forceinline__ unsigned cvt_pk_bf16(float lo, float hi) {
  unsigned r;
  asm("v_cvt_pk_bf16_f32 %0, %1, %2" : "=v"(r) : "v"(lo), "v"(hi));
  return r;
}

static __device__ __forceinline__ float max3f(float a, float b, float c) {
  return fmaxf(fmaxf(a, b), c);   // clang fuses to v_max3_f32 (T17)
}

static __device__ __forceinline__ void gload_lds16(const void* g, void* l) {
  __builtin_amdgcn_global_load_lds((__attribute__((address_space(1))) void*)g,
                                   (__attribute__((address_space(3))) void*)l,
                                   16, 0, 0);
}

// ---- fused prep: x->bf16 cvt (blocks 0..1023) + both weight transposes ----
__global__ __launch_bounds__(256) void k_prep(
    const float4* __restrict__ x4, ushort4* __restrict__ xb4,
    const float* __restrict__ qkv_w, unsigned short* __restrict__ WqT,
    const float* __restrict__ proj_w, unsigned short* __restrict__ WpT) {
  const int blk = blockIdx.x;
  if (blk < 1024) {
    const int n4 = MTOT * DMODEL / 4;
    const int stride = 1024 * 256;
    for (int i = blk * 256 + threadIdx.x; i < n4; i += stride) {
      float4 v = x4[i];
      ushort4 o;
      o.x = f2bf(v.x); o.y = f2bf(v.y); o.z = f2bf(v.z); o.w = f2bf(v.w);
      xb4[i] = o;
    }
    return;
  }
  __shared__ float tile[32][33];
  const float* in; unsigned short* out; int C, scaleN, bx, by;
  if (blk < 1024 + 1728) {
    const int l = blk - 1024; bx = l % 72; by = l / 72;
    in = qkv_w; out = WqT; C = NQKV; scaleN = DMODEL;
  } else {
    const int l = blk - 2752; bx = l % 24; by = l / 24;
    in = proj_w; out = WpT; C = DMODEL; scaleN = 0;
  }
  const int R = DMODEL;
  const int tx = threadIdx.x & 31, ty = threadIdx.x >> 5;
  const int c0 = bx * 32, r0 = by * 32;
#pragma unroll
  for (int i = 0; i < 4; ++i)
    tile[ty + i * 8][tx] = in[(size_t)(r0 + ty + i * 8) * C + c0 + tx];
  __syncthreads();
#pragma unroll
  for (int i = 0; i < 4; ++i) {
    const int n = c0 + ty + i * 8;  // original column = output row
    float v = tile[tx][ty + i * 8];
    if (n < scaleN) v *= QSCALE;
    out[(size_t)n * R + r0 + tx] = f2bf(v);
  }
}

// ---- GEMM C[M,N] = A[M,K] * Bt[N,K]^T, bf16 in, f32 accum (R12 exact) ----
template <int MODE>
__global__ __launch_bounds__(256, 4) void k_gemm_bt(
    const unsigned short* __restrict__ A, const unsigned short* __restrict__ Bt,
    int M, int N, int K,
    float* __restrict__ outF, const float* __restrict__ bias,
    unsigned short* __restrict__ QK, unsigned short* __restrict__ Vt) {
  __shared__ __align__(16) unsigned short As[128 * 64];  // 16 KB
  __shared__ __align__(16) unsigned short Bs[128 * 64];  // 16 KB
  const int tid = threadIdx.x;
  const int lane = tid & 63, wid = tid >> 6;
  const int ln15 = lane & 15, lh = lane >> 4;
  const int wr = wid >> 1, wc = wid & 1;
  const int m0 = blockIdx.x * 128, n0 = blockIdx.y * 128;
  f32x4 acc[4][4] = {};
  const int srow = lane >> 3;
  const int sblk = ((lane & 7) ^ srow) * 8;
  const int swz = (ln15 & 7) << 3;
  const int nk = K >> 6;

  for (int kt = 0; kt < nk; ++kt) {
    const int k0 = kt * 64;
#pragma unroll
    for (int c = 0; c < 4; ++c) {
      const int ch = wid * 4 + c;
      const int row = ch * 8 + srow;
      gload_lds16(A + (size_t)(m0 + row) * K + k0 + sblk, &As[ch * 512]);
      gload_lds16(Bt + (size_t)(n0 + row) * K + k0 + sblk, &Bs[ch * 512]);
    }
    __syncthreads();
#pragma unroll
    for (int kk = 0; kk < 2; ++kk) {
      const int kc = kk * 32 + lh * 8;
      bf16x8 af[4], bfv[4];
#pragma unroll
      for (int mt = 0; mt < 4; ++mt)
        af[mt] = *reinterpret_cast<const bf16x8*>(
            &As[(wr * 64 + mt * 16 + ln15) * 64 + (kc ^ swz)]);
#pragma unroll
      for (int nn = 0; nn < 4; ++nn)
        bfv[nn] = *reinterpret_cast<const bf16x8*>(
            &Bs[(wc * 64 + nn * 16 + ln15) * 64 + (kc ^ swz)]);
#pragma unroll
      for (int mt = 0; mt < 4; ++mt)
#pragma unroll
        for (int nn = 0; nn < 4; ++nn)
          acc[mt][nn] = __builtin_amdgcn_mfma_f32_16x16x32_bf16(af[mt], bfv[nn], acc[mt][nn], 0, 0, 0);
    }
    __syncthreads();
  }

#pragma unroll
  for (int mt = 0; mt < 4; ++mt) {
#pragma unroll
    for (int nn = 0; nn < 4; ++nn) {
      const int nb = n0 + wc * 64 + nn * 16;
      const int mb = m0 + wr * 64 + mt * 16 + lh * 4;
      if (MODE == 0) {
#pragma unroll
        for (int r = 0; r < 4; ++r)
          outF[(size_t)(mb + r) * N + nb + ln15] = acc[mt][nn][r] + bias[nb + ln15];
      } else if (nb < NQK) {
#pragma unroll
        for (int r = 0; r < 4; ++r)
          QK[(size_t)(mb + r) * NQK + nb + ln15] = f2bf(acc[mt][nn][r]);
      } else {
        const int rr = nb + ln15 - NQK;
        const int h = rr >> 6, d = rr & 63;
        const int b = mb >> 10, nr0 = mb & 1023;
        ushort4 u;
        u.x = f2bf(acc[mt][nn][0]); u.y = f2bf(acc[mt][nn][1]);
        u.z = f2bf(acc[mt][nn][2]); u.w = f2bf(acc[mt][nn][3]);
        *reinterpret_cast<ushort4*>(
            &Vt[(((size_t)b * NHEAD + h) * HDIM + d) * SEQ + nr0]) = u;
      }
    }
  }
}

// ---- fused flash attention: dual 16-q tiles per wave (QBLK=256) ----
// 8 waves; each wave owns q-tiles {qb*256 + w*16, qb*256 + 128 + w*16}.
// One K/V staging + 2 barriers now serve 32 q-rows (staging/q, barriers/q
// halve vs R14); PV shares each bv read across both tiles. All 16x16 fragment
// layouts / swizzles / softmax structure identical to the proven R14 kernel.
// LDS 53.2 KB -> 3 blocks/CU (R14: 3-vs-4 blocks measured ~null).
__global__ __launch_bounds__(512) void k_attn(
    const unsigned short* __restrict__ QKn, const unsigned short* __restrict__ Vt,
    unsigned short* __restrict__ O) {
  __shared__ __align__(16) unsigned short Ks[64 * 64];        // [kpos][d], swizzled
  __shared__ __align__(16) unsigned short Vs[64 * 64];        // [d][kpos], swizzled
  __shared__ __align__(16) unsigned short Ps[8][2][16 * 72];  // per-wave,per-tile P
  const int tid = threadIdx.x;
  const int lane = tid & 63, w = tid >> 6;
  const int ln15 = lane & 15, lh = lane >> 4;
  // XCD grouping: 768 blocks, 96 per XCD; qb fastest within a head
  const int o = blockIdx.x;
  const int sid = (o & 7) * 96 + (o >> 3);
  const int qb = sid & 3;
  const int bhid = sid >> 2;
  const int h = bhid % NHEAD;
  const int b = bhid / NHEAD;
  const size_t bh = (size_t)(b * NHEAD + h);
  const unsigned short* Kbase = QKn + (size_t)(b * SEQ) * NQK + DMODEL + h * HDIM;
  const unsigned short* Vbase = Vt + bh * HDIM * SEQ;

  const int srow = lane >> 3;
  const int sblk = ((lane & 7) ^ srow) * 8;
  const int swz = (ln15 & 7) << 3;

  // Q fragments for both tiles (B-operand): lane ln15 = q-col
  bf16x8 aq[2][2];
#pragma unroll
  for (int tl = 0; tl < 2; ++tl) {
    const unsigned short* Qb =
        QKn + (size_t)(b * SEQ + qb * 256 + tl * 128 + w * 16) * NQK + h * HDIM;
#pragma unroll
    for (int ch = 0; ch < 2; ++ch)
      aq[tl][ch] = *reinterpret_cast<const bf16x8*>(Qb + (size_t)ln15 * NQK + ch * 32 + lh * 8);
  }

  bf16x8 onesb;
#pragma unroll
  for (int i = 0; i < 8; ++i) onesb[i] = (__bf16)1.0f;

  f32x4 acc[2][4] = {};
  f32x4 accl[2] = {};        // row-sums; elem r <-> q-row lh*4+r
  float mr[2] = {0.f, 0.f};  // running max (log2 domain)

  for (int kb = 0; kb < SEQ / 64; ++kb) {
    {  // stage K/V tile kb (8 chunks each; wave w takes chunk w)
      const int row = w * 8 + srow;
      gload_lds16(Kbase + (size_t)(kb * 64 + row) * NQK + sblk, &Ks[w * 512]);
      gload_lds16(Vbase + (size_t)row * SEQ + kb * 64 + sblk, &Vs[w * 512]);
    }
    __syncthreads();

#pragma unroll
    for (int tl = 0; tl < 2; ++tl) {
      // S^T = K Q^T with C = -mr
      const float nmr = -mr[tl];
      f32x4 sv[4];
#pragma unroll
      for (int t = 0; t < 4; ++t) { sv[t][0] = nmr; sv[t][1] = nmr; sv[t][2] = nmr; sv[t][3] = nmr; }
      __builtin_amdgcn_s_setprio(1);
#pragma unroll
      for (int t = 0; t < 4; ++t) {
#pragma unroll
        for (int ch = 0; ch < 2; ++ch) {
          bf16x8 bk = *reinterpret_cast<const bf16x8*>(
              &Ks[(t * 16 + ln15) * 64 + ((ch * 32 + lh * 8) ^ swz)]);
          sv[t] = __builtin_amdgcn_mfma_f32_16x16x32_bf16(bk, aq[tl][ch], sv[t], 0, 0, 0);
        }
      }
      __builtin_amdgcn_s_setprio(0);

      // in-lane partial max: balanced max3 tree
      float pm;
      {
        const float g0 = max3f(sv[0][0], sv[0][1], sv[0][2]);
        const float g1 = max3f(sv[0][3], sv[1][0], sv[1][1]);
        const float g2 = max3f(sv[1][2], sv[1][3], sv[2][0]);
        const float g3 = max3f(sv[2][1], sv[2][2], sv[2][3]);
        const float g4 = max3f(sv[3][0], sv[3][1], sv[3][2]);
        pm = fmaxf(max3f(g0, g1, g2), max3f(g3, g4, sv[3][3]));
      }
      // defer-max: rescale only when some row grew past +8
      if (__any(pm > 8.f)) {
        float bmf = pm;
        bmf = fmaxf(bmf, __shfl_xor(bmf, 16));
        bmf = fmaxf(bmf, __shfl_xor(bmf, 32));
        const float delta = fmaxf(bmf, 0.f);
        const float al = __builtin_amdgcn_exp2f(-delta);
#pragma unroll
        for (int t = 0; t < 4; ++t)
#pragma unroll
          for (int r = 0; r < 4; ++r) sv[t][r] -= delta;
        mr[tl] += delta;
        float alq[4];
#pragma unroll
        for (int r = 0; r < 4; ++r) alq[r] = __shfl(al, lh * 4 + r);
#pragma unroll
        for (int dt = 0; dt < 4; ++dt)
#pragma unroll
          for (int r = 0; r < 4; ++r) acc[tl][dt][r] *= alq[r];
#pragma unroll
        for (int r = 0; r < 4; ++r) accl[tl][r] *= alq[r];
      }

#pragma unroll
      for (int t = 0; t < 4; ++t)
#pragma unroll
        for (int r = 0; r < 4; ++r) sv[t][r] = __builtin_amdgcn_exp2f(sv[t][r]);

      // pack P -> LDS
#pragma unroll
      for (int t = 0; t < 4; ++t) {
        uint2 u;
        u.x = cvt_pk_bf16(sv[t][0], sv[t][1]);
        u.y = cvt_pk_bf16(sv[t][2], sv[t][3]);
        *reinterpret_cast<uint2*>(&Ps[w][tl][ln15 * 72 + t * 16 + lh * 4]) = u;
      }
    }

    // joint PV: bv reads shared across both tiles
    bf16x8 ap[2][2];
#pragma unroll
    for (int tl = 0; tl < 2; ++tl)
#pragma unroll
      for (int ch = 0; ch < 2; ++ch)
        ap[tl][ch] = *reinterpret_cast<const bf16x8*>(&Ps[w][tl][ln15 * 72 + ch * 32 + lh * 8]);
    __builtin_amdgcn_s_setprio(1);
#pragma unroll
    for (int ch = 0; ch < 2; ++ch) {  // row-sum MFMAs
      accl[0] = __builtin_amdgcn_mfma_f32_16x16x32_bf16(ap[0][ch], onesb, accl[0], 0, 0, 0);
      accl[1] = __builtin_amdgcn_mfma_f32_16x16x32_bf16(ap[1][ch], onesb, accl[1], 0, 0, 0);
    }
#pragma unroll
    for (int dt = 0; dt < 4; ++dt) {
#pragma unroll
      for (int ch = 0; ch < 2; ++ch) {
        bf16x8 bv = *reinterpret_cast<const bf16x8*>(
            &Vs[(dt * 16 + ln15) * 64 + ((ch * 32 + lh * 8) ^ swz)]);
        acc[0][dt] = __builtin_amdgcn_mfma_f32_16x16x32_bf16(ap[0][ch], bv, acc[0][dt], 0, 0, 0);
        acc[1][dt] = __builtin_amdgcn_mfma_f32_16x16x32_bf16(ap[1][ch], bv, acc[1][dt], 0, 0, 0);
      }
    }
    __builtin_amdgcn_s_setprio(0);
    __syncthreads();
  }

#pragma unroll
  for (int tl = 0; tl < 2; ++tl) {
    const int qrow = qb * 256 + tl * 128 + w * 16 + lh * 4;
#pragma unroll
    for (int dt = 0; dt < 4; ++dt)
#pragma unroll
      for (int r = 0; r < 4; ++r)
        O[((size_t)b * SEQ + qrow + r) * DMODEL + h * 64 + dt * 16 + ln15] =
            f2bf(acc[tl][dt][r] / accl[tl][r]);
  }
}

extern "C" void kernel_launch(void* const* d_in, const int* in_sizes, int n_in,
                              void* d_out, int out_size, void* d_ws, size_t ws_size,
                              hipStream_t stream) {
  const float* x      = (const float*)d_in[0];
  const float* qkv_w  = (const float*)d_in[1];
  const float* proj_w = (const float*)d_in[2];
  const float* proj_b = (const float*)d_in[3];
  float* out = (float*)d_out;

  char* ws = (char*)d_ws;
  const size_t SZ_XB   = (size_t)MTOT * DMODEL * 2;   // x bf16; reused as attn-out bf16
  const size_t SZ_WQT  = (size_t)NQKV * DMODEL * 2;
  const size_t SZ_WPT  = (size_t)DMODEL * DMODEL * 2;
  const size_t SZ_QK   = (size_t)MTOT * NQK * 2;      // natural Q|K [m][1536]
  const size_t SZ_VT   = (size_t)BB * NHEAD * HDIM * SEQ * 2;
  unsigned short* Xb   = (unsigned short*)ws;
  unsigned short* WqT  = (unsigned short*)(ws + SZ_XB);
  unsigned short* WpT  = (unsigned short*)(ws + SZ_XB + SZ_WQT);
  unsigned short* QKn  = (unsigned short*)(ws + SZ_XB + SZ_WQT + SZ_WPT);
  unsigned short* Vt   = (unsigned short*)(ws + SZ_XB + SZ_WQT + SZ_WPT + SZ_QK);
  if (ws_size < SZ_XB + SZ_WQT + SZ_WPT + SZ_QK + SZ_VT) return;

  // 1) fused prep: x->bf16 + both weight transposes (Q-cols pre-scaled by QSCALE)
  k_prep<<<3328, 256, 0, stream>>>((const float4*)x, (ushort4*)Xb,
                                   qkv_w, WqT, proj_w, WpT);
  // 2) QKV projection -> natural Q|K [m][1536] + packed V^T. 128^2 tiles, m-fastest.
  k_gemm_bt<1><<<dim3(MTOT / 128, NQKV / 128), 256, 0, stream>>>(
      Xb, WqT, MTOT, NQKV, DMODEL, nullptr, nullptr, QKn, Vt);
  // 3) fused attention -> Oattn (reuses Xb region; Xb is dead after step 2)
  k_attn<<<BB * NHEAD * 4, 512, 0, stream>>>(QKn, Vt, Xb);
  // 4) output projection + bias -> f32 out
  k_gemm_bt<0><<<dim3(MTOT / 128, DMODEL / 128), 256, 0, stream>>>(
      Xb, WpT, MTOT, DMODEL, DMODEL, out, proj_b, nullptr, nullptr);
}